// Round 15
// baseline (142.578 us; speedup 1.0000x reference)
//
#include <hip/hip_runtime.h>
#include <stdint.h>

#define DEV __device__ __forceinline__

typedef __bf16 bf16x8 __attribute__((ext_vector_type(8)));
typedef float  f32x4  __attribute__((ext_vector_type(4)));
typedef short  s16x8  __attribute__((ext_vector_type(8)));

constexpr int Bb   = 2;
constexpr int Nn   = 2048;
constexpr int DIMc = 1024;
constexpr int Hh   = 16;
constexpr int DHc  = 64;
constexpr int BN   = Bb * Nn;        // 4096
constexpr int QKVC = 3 * Hh * DHc;   // 3072

// f32 -> bf16 (RNE)
DEV ushort f2b(float f) {
  uint32_t u = __float_as_uint(f);
  u += 0x7fffu + ((u >> 16) & 1u);
  return (ushort)(u >> 16);
}

// async global->LDS, 16B per lane. LDS dest must be wave-uniform base (+lane*16 implicit).
DEV void gload16(const void* g, void* l) {
  __builtin_amdgcn_global_load_lds(
      (const __attribute__((address_space(1))) void*)(uintptr_t)g,
      (__attribute__((address_space(3))) void*)(uint32_t)(uintptr_t)l,
      16, 0, 0);
}

DEV f32x4 mfma16(bf16x8 a, bf16x8 b, f32x4 c) {
  return __builtin_amdgcn_mfma_f32_16x16x32_bf16(a, b, c, 0, 0, 0);
}

DEV uint32_t cvtpk(float lo, float hi) {
  uint32_t r;
  asm("v_cvt_pk_bf16_f32 %0, %1, %2" : "=v"(r) : "v"(lo), "v"(hi));
  return r;
}

// ---------------- prep kernels (R9-verified) ----------------

__global__ void k_cast_x(const float* __restrict__ x, ushort* __restrict__ xb,
                         const float* __restrict__ rope, float2* __restrict__ csT) {
  int i = blockIdx.x * 256 + threadIdx.x;
  size_t base = (size_t)i * 8;
  s16x8 v;
#pragma unroll
  for (int j = 0; j < 8; ++j) v[j] = (short)f2b(x[base + j]);
  *(s16x8*)(xb + base) = v;
  if (i < Nn * DHc) {
    float t = rope[i];
    float s, c;
    sincosf(t, &s, &c);
    csT[i] = make_float2(c, s);
  }
}

__global__ void k_transpose_cast(const float* __restrict__ src, ushort* __restrict__ dst,
                                 int K, int Ncols) {
  __shared__ float tile[32][33];
  int nb = blockIdx.x * 32, kb = blockIdx.y * 32;
  int tx = threadIdx.x, ty = threadIdx.y;
#pragma unroll
  for (int i = 0; i < 4; ++i) {
    int k = ty + i * 8;
    tile[k][tx] = src[(size_t)(kb + k) * Ncols + nb + tx];
  }
  __syncthreads();
#pragma unroll
  for (int i = 0; i < 4; ++i) {
    int n = ty + i * 8;
    dst[(size_t)(nb + n) * K + kb + tx] = f2b(tile[tx][n]);
  }
}

// ---------------- GEMM1 v5: 256x256 tile, BK=32, 8 waves, PROVEN 3-buffer pipeline ----------------
// Scale-up of the R6/R9-verified core: same 3-buffer / 1-barrier / counted-vmcnt ledger,
// same chunk-XOR swizzle; 2x tile in both dims, 8 waves (2M x 4N), wave tile 128x64.
// Per SIMD per K-step: 2 waves x 32 MFMA (~1240cy) vs ~12 ds_read + 4 gload (~300cy)
// -> MFMA-dominated barrier windows (the 128x128 core was ~1:1). LDS 96KB, 1 block/CU.
// grid (12,16) = 192 blocks, T1 XCD swizzle (24 blocks/XCD contiguous chunk).
__global__ __launch_bounds__(512, 2) void k_gemm_qkv(
    const ushort* __restrict__ xb, const ushort* __restrict__ wT,
    const float2* __restrict__ csT,
    ushort* __restrict__ Qd, ushort* __restrict__ Kd, ushort* __restrict__ Vd) {
  __shared__ ushort lA[3 * 256 * 32];   // 48 KB
  __shared__ ushort lB[3 * 256 * 32];   // 48 KB
  const int tid = threadIdx.x;          // 0..511
  const int lane = tid & 63, w = tid >> 6;
  const int wm = w >> 2, wn = w & 3;    // 2M x 4N
  const int g = lane >> 4, l16 = lane & 15;
  const int i = blockIdx.x + blockIdx.y * 12;
  const int c = i & 7, li = i >> 3;     // c = XCD (round-robin dispatch), li in [0,24)
  const int bx = (c & 1) * 6 + li % 6;  // 2x4 chunk grid of 6x x 4y tiles
  const int by = (c >> 1) * 4 + li / 6;
  const int rowBase = by * 256, colBase = bx * 256;
  constexpr int BUF = 256 * 32;         // ushorts per buffer

  f32x4 acc[8][4];
  const f32x4 zero = {0.f, 0.f, 0.f, 0.f};
#pragma unroll
  for (int a = 0; a < 8; ++a)
#pragma unroll
    for (int b = 0; b < 4; ++b) acc[a][b] = zero;

  // staging: 1024 chunk-slots (256 rows x 4 chunks) / 512 threads = 2 slots each.
  // slot cs = s*512 + tid -> row = cs>>2, phys chunk cs&3 holds global chunk (cs&3)^((row>>1)&3).
  const int r0 = tid >> 2,        k0c = (tid & 3) ^ ((r0 >> 1) & 3);
  const int r1 = (512 + tid) >> 2, k1c = (tid & 3) ^ ((r1 >> 1) & 3);
  const ushort* gA0 = xb + (size_t)(rowBase + r0) * DIMc + k0c * 8;
  const ushort* gA1 = xb + (size_t)(rowBase + r1) * DIMc + k1c * 8;
  const ushort* gB0 = wT + (size_t)(colBase + r0) * DIMc + k0c * 8;
  const ushort* gB1 = wT + (size_t)(colBase + r1) * DIMc + k1c * 8;
  const size_t o0 = (size_t)(0 * 512 + w * 64) * 8;   // wave-uniform LDS dest (lane*16 implicit)
  const size_t o1 = (size_t)(1 * 512 + w * 64) * 8;

  // prologue: tiles 0,1 -> buf 0,1 (4 loads/thread each)
  gload16(gA0,      lA + o0);        gload16(gA1,      lA + o1);
  gload16(gB0,      lB + o0);        gload16(gB1,      lB + o1);
  gload16(gA0 + 32, lA + BUF + o0);  gload16(gA1 + 32, lA + BUF + o1);
  gload16(gB0 + 32, lB + BUF + o0);  gload16(gB1 + 32, lB + BUF + o1);
  asm volatile("s_waitcnt vmcnt(4)" ::: "memory");   // tile0 complete; tile1 in flight
  __builtin_amdgcn_s_barrier();

  int cur = 0;
  for (int k0 = 0; k0 < DIMc; k0 += 32) {
    const ushort* cA = lA + cur * BUF;
    const ushort* cB = lB + cur * BUF;

    bf16x8 aF[8], bF[4];
#pragma unroll
    for (int mf = 0; mf < 8; ++mf) {
      int r = wm * 128 + mf * 16 + l16;
      aF[mf] = *(const bf16x8*)&cA[r * 32 + ((g ^ ((r >> 1) & 3)) << 3)];
    }
#pragma unroll
    for (int nf = 0; nf < 4; ++nf) {
      int r2 = wn * 64 + nf * 16 + l16;
      bF[nf] = *(const bf16x8*)&cB[r2 * 32 + ((g ^ ((r2 >> 1) & 3)) << 3)];
    }

    const int kn = k0 + 64;
    if (kn < DIMc) {
      int st = cur + 2; if (st >= 3) st -= 3;
      ushort* nA = lA + st * BUF;
      ushort* nB = lB + st * BUF;
      gload16(gA0 + kn, nA + o0);  gload16(gA1 + kn, nA + o1);
      gload16(gB0 + kn, nB + o0);  gload16(gB1 + kn, nB + o1);
    }

#pragma unroll
    for (int mf = 0; mf < 8; ++mf)
#pragma unroll
      for (int nf = 0; nf < 4; ++nf)
        acc[mf][nf] = mfma16(aF[mf], bF[nf], acc[mf][nf]);

    if (kn < DIMc) {
      asm volatile("s_waitcnt vmcnt(4)" ::: "memory");   // tile j+1 complete, j+2 in flight
    } else if (k0 + 32 < DIMc) {
      asm volatile("s_waitcnt vmcnt(0)" ::: "memory");
    }
    asm volatile("s_waitcnt lgkmcnt(0)" ::: "memory");   // own reads drained before buffer reuse
    __builtin_amdgcn_s_barrier();
    cur += 1; if (cur == 3) cur = 0;
  }

  // epilogue: rotary + scatter to Q (scaled), K, V^T
#pragma unroll
  for (int mf = 0; mf < 8; ++mf) {
#pragma unroll
    for (int nf = 0; nf < 4; ++nf) {
      int col = colBase + wn * 64 + nf * 16 + l16;   // 0..3071
      int sel = col >> 10, hc = col & 1023;
      int h = hc >> 6, d = hc & 63;
      float sgn = (d & 1) ? 1.f : -1.f;
#pragma unroll
      for (int r = 0; r < 4; ++r) {
        float t  = acc[mf][nf][r];
        float tp = __shfl_xor(t, 1);
        int row = rowBase + wm * 128 + mf * 16 + 4 * g + r;
        int b = row >> 11, n = row & 2047;
        float2 cs = csT[n * 64 + d];
        float rv = t * cs.x + sgn * tp * cs.y;
        if (sel == 0) {
          Qd[((size_t)(b * Hh + h) * Nn + n) * DHc + d] = f2b(rv * 0.125f);
        } else if (sel == 1) {
          Kd[((size_t)(b * Hh + h) * Nn + n) * DHc + d] = f2b(rv);
        } else {
          Vd[((size_t)(b * Hh + h) * DHc + d) * Nn + n] = f2b(rv);
        }
      }
    }
  }
}

// ---------------- attention (R14-verified: R9 paired structure + T1 XCD swizzle) ----------------

DEV void stageKV(const ushort* __restrict__ Kh, const ushort* __restrict__ Vh,
                 ushort* lKb, ushort* lVb, int kt, int tid, int w) {
#pragma unroll
  for (int s = 0; s < 2; ++s) {
    int c = s * 256 + tid;
    int row = c >> 3, jst = c & 7;
    int jl = jst ^ (row & 7);
    gload16(Kh + (size_t)(kt * 64 + row) * DHc + jl * 8,
            lKb + (size_t)(s * 256 + w * 64) * 8);
    gload16(Vh + (size_t)row * Nn + kt * 64 + jl * 8,
            lVb + (size_t)(s * 256 + w * 64) * 8);
  }
}

DEV void attn_step(const ushort* lKc, const ushort* lVc, char* lPw,
                   const bf16x8 (&q)[2], f32x4 (&o)[4], float& m, float& l,
                   int kBase, int qg, bool diag, int g, int l16) {
  const f32x4 zero = {0.f, 0.f, 0.f, 0.f};
  f32x4 s[4];
#pragma unroll
  for (int jt = 0; jt < 4; ++jt) s[jt] = zero;

#pragma unroll
  for (int jt = 0; jt < 4; ++jt) {
    int jr = jt * 16 + l16;
#pragma unroll
    for (int d0 = 0; d0 < 2; ++d0) {
      bf16x8 kb = *(const bf16x8*)&lKc[jr * 64 + (((d0 * 4 + g) ^ (jr & 7)) << 3)];
      s[jt] = mfma16(kb, q[d0], s[jt]);
    }
  }

  if (diag) {
#pragma unroll
    for (int jt = 0; jt < 4; ++jt)
#pragma unroll
      for (int r = 0; r < 4; ++r) {
        int j = kBase + jt * 16 + 4 * g + r;
        if (j > qg) s[jt][r] = -3.0e38f;
      }
  }

  float tmax = fmaxf(fmaxf(fmaxf(s[0][0], s[0][1]), fmaxf(s[0][2], s[0][3])),
                     fmaxf(fmaxf(s[1][0], s[1][1]), fmaxf(s[1][2], s[1][3])));
  tmax = fmaxf(tmax, fmaxf(fmaxf(fmaxf(s[2][0], s[2][1]), fmaxf(s[2][2], s[2][3])),
                           fmaxf(fmaxf(s[3][0], s[3][1]), fmaxf(s[3][2], s[3][3]))));
  tmax = fmaxf(tmax, __shfl_xor(tmax, 16));
  tmax = fmaxf(tmax, __shfl_xor(tmax, 32));

  if (!__all(tmax <= m + 8.f)) {
    float mnew = fmaxf(m, tmax);
    float sc = __expf(m - mnew);
#pragma unroll
    for (int dt = 0; dt < 4; ++dt) o[dt] *= sc;
    l *= sc;
    m = mnew;
  }

  float ps = 0.f;
#pragma unroll
  for (int jt = 0; jt < 4; ++jt)
#pragma unroll
    for (int r = 0; r < 4; ++r) {
      float p = __expf(s[jt][r] - m);
      s[jt][r] = p;
      ps += p;
    }
  ps += __shfl_xor(ps, 16);
  ps += __shfl_xor(ps, 32);
  l += ps;

  const int sw = (l16 & 7) << 4;
  char* prow = lPw + l16 * 128;
#pragma unroll
  for (int jt = 0; jt < 4; ++jt) {
    int jo = (jt * 16 + 4 * g) * 2;
    *(uint32_t*)(prow + (jo ^ sw))       = cvtpk(s[jt][0], s[jt][1]);
    *(uint32_t*)(prow + ((jo + 4) ^ sw)) = cvtpk(s[jt][2], s[jt][3]);
  }

  bf16x8 pa[2];
#pragma unroll
  for (int jh = 0; jh < 2; ++jh)
    pa[jh] = *(const bf16x8*)(prow + (((jh * 32 + 8 * g) * 2) ^ sw));
#pragma unroll
  for (int dt = 0; dt < 4; ++dt) {
    int d = dt * 16 + l16;
#pragma unroll
    for (int jh = 0; jh < 2; ++jh) {
      bf16x8 vb = *(const bf16x8*)&lVc[d * 64 + (((jh * 4 + g) ^ (d & 7)) << 3)];
      o[dt] = mfma16(vb, pa[jh], o[dt]);
    }
  }
}

DEV void attn_epi(ushort* __restrict__ ao, int bh, int n, int g,
                  f32x4 (&o)[4], float l) {
  const int b = bh >> 4, h = bh & 15;
  float inv = 1.f / l;
  ushort* dst = ao + (size_t)(b * Nn + n) * (Hh * DHc) + h * 64;
#pragma unroll
  for (int dt = 0; dt < 4; ++dt) {
    uint2 pkd;
    pkd.x = cvtpk(o[dt][0] * inv, o[dt][1] * inv);
    pkd.y = cvtpk(o[dt][2] * inv, o[dt][3] * inv);
    *(uint2*)(dst + dt * 16 + 4 * g) = pkd;
  }
}

__global__ __launch_bounds__(256) void k_attn(
    const ushort* __restrict__ Qd, const ushort* __restrict__ Kd,
    const ushort* __restrict__ Vd, ushort* __restrict__ ao) {
  __shared__ ushort lK[2][64 * 64];
  __shared__ ushort lV[2][64 * 64];
  __shared__ char   lP[4][16 * 128];
  const int tid = threadIdx.x;
  const int lane = tid & 63, w = tid >> 6;
  const int g = lane >> 4, l16 = lane & 15;
  const int i = blockIdx.x + blockIdx.y * 16;
  const int c = i & 7, li = i >> 3;
  const int bh = c * 4 + (li >> 4);
  const int p = li & 15;
  const int tA = p, tB = 31 - p;
  const int last = tB;
  const ushort* Qh = Qd + (size_t)bh * Nn * DHc;
  const ushort* Kh = Kd + (size_t)bh * Nn * DHc;
  const ushort* Vh = Vd + (size_t)bh * DHc * Nn;

  const int qgA = tA * 64 + w * 16 + l16;
  const int qgB = tB * 64 + w * 16 + l16;

  bf16x8 qA[2], qB[2];
#pragma unroll
  for (int d0 = 0; d0 < 2; ++d0) {
    qA[d0] = *(const bf16x8*)(Qh + (size_t)qgA * DHc + d0 * 32 + g * 8);
    qB[d0] = *(const bf16x8*)(Qh + (size_t)qgB * DHc + d0 * 32 + g * 8);
  }

  const f32x4 zero = {0.f, 0.f, 0.f, 0.f};
  f32x4 oA[4], oB[4];
#pragma unroll
  for (int dt = 0; dt < 4; ++dt) { oA[dt] = zero; oB[dt] = zero; }
  float mA = -3.0e38f, lA_ = 0.f, mB = -3.0e38f, lB_ = 0.f;

  stageKV(Kh, Vh, lK[0], lV[0], 0, tid, w);

  for (int kt = 0; kt <= last; ++kt) {
    const int cur = kt & 1;
    if (kt < last) {
      stageKV(Kh, Vh, lK[cur ^ 1], lV[cur ^ 1], kt + 1, tid, w);
      asm volatile("s_waitcnt vmcnt(4)" ::: "memory");
    } else {
      asm volatile("s_waitcnt vmcnt(0)" ::: "memory");
    }
    __builtin_amdgcn_s_barrier();

    attn_step(lK[cur], lV[cur], lP[w], qB, oB, mB, lB_, kt * 64, qgB, kt == tB, g, l16);
    if (kt <= tA)
      attn_step(lK[cur], lV[cur], lP[w], qA, oA, mA, lA_, kt * 64, qgA, kt == tA, g, l16);

    __builtin_amdgcn_s_barrier();
  }

  attn_epi(ao, bh, qgA, g, oA, lA_);
  attn_epi(ao, bh, qgB, g, oB, lB_);
}

// ---------------- GEMM2 (R14-verified): 64x128 tiles + T1 XCD swizzle ----------------
__global__ __launch_bounds__(256) void k_gemm_out(
    const ushort* __restrict__ ao, const ushort* __restrict__ wT,
    const float* __restrict__ bias, float* __restrict__ out) {
  __shared__ ushort lA[3 * 64 * 32];
  __shared__ ushort lB[3 * 128 * 32];
  const int tid = threadIdx.x;
  const int lane = tid & 63, w = tid >> 6;
  const int g = lane >> 4, l16 = lane & 15;
  const int i = blockIdx.x + blockIdx.y * 8;
  const int c = i & 7, li = i >> 3;
  const int bx = (c & 3) * 2 + (li & 1);
  const int by = (c >> 2) * 32 + (li >> 1);
  const int rowBase = by * 64, colBase = bx * 128;

  f32x4 acc[4][2];
  const f32x4 zero = {0.f, 0.f, 0.f, 0.f};
#pragma unroll
  for (int i2 = 0; i2 < 4; ++i2) { acc[i2][0] = zero; acc[i2][1] = zero; }

  const int arow = tid >> 2, akc = (tid & 3) ^ ((arow >> 1) & 3);
  const int b1row = 64 + arow, b1kc = (tid & 3) ^ ((b1row >> 1) & 3);
  const ushort* gA  = ao + (size_t)(rowBase + arow) * DIMc + akc * 8;
  const ushort* gB0 = wT + (size_t)(colBase + arow) * DIMc + akc * 8;
  const ushort* gB1 = wT + (size_t)(colBase + b1row) * DIMc + b1kc * 8;
  const size_t oA  = (size_t)w * 512;
  const size_t oB0 = (size_t)w * 512;
  const size_t oB1 = 2048 + (size_t)w * 512;
  constexpr int BUFA = 64 * 32, BUFB = 128 * 32;

  gload16(gA,      lA + oA);         gload16(gB0,      lB + oB0);         gload16(gB1,      lB + oB1);
  gload16(gA + 32, lA + BUFA + oA);  gload16(gB0 + 32, lB + BUFB + oB0);  gload16(gB1 + 32, lB + BUFB + oB1);
  asm volatile("s_waitcnt vmcnt(3)" ::: "memory");
  __builtin_amdgcn_s_barrier();

  int cur = 0;
  for (int k0 = 0; k0 < DIMc; k0 += 32) {
    const ushort* cA = lA + cur * BUFA;
    const ushort* cB = lB + cur * BUFB;

    bf16x8 af[4], bfr[2];
#pragma unroll
    for (int f = 0; f < 4; ++f) {
      int r = f * 16 + l16;
      af[f] = *(const bf16x8*)&cA[r * 32 + ((g ^ ((r >> 1) & 3)) << 3)];
    }
#pragma unroll
    for (int f = 0; f < 2; ++f) {
      int r2 = w * 32 + f * 16 + l16;
      bfr[f] = *(const bf16x8*)&cB[r2 * 32 + ((g ^ ((r2 >> 1) & 3)) << 3)];
    }

    const int kn = k0 + 64;
    if (kn < DIMc) {
      int st = cur + 2; if (st >= 3) st -= 3;
      gload16(gA + kn,  lA + st * BUFA + oA);
      gload16(gB0 + kn, lB + st * BUFB + oB0);
      gload16(gB1 + kn, lB + st * BUFB + oB1);
    }

#pragma unroll
    for (int i2 = 0; i2 < 4; ++i2)
#pragma unroll
      for (int j = 0; j < 2; ++j)
        acc[i2][j] = mfma16(af[i2], bfr[j], acc[i2][j]);

    if (kn < DIMc) {
      asm volatile("s_waitcnt vmcnt(3)" ::: "memory");
    } else if (k0 + 32 < DIMc) {
      asm volatile("s_waitcnt vmcnt(0)" ::: "memory");
    }
    asm volatile("s_waitcnt lgkmcnt(0)" ::: "memory");
    __builtin_amdgcn_s_barrier();
    cur += 1; if (cur == 3) cur = 0;
  }

#pragma unroll
  for (int fm = 0; fm < 4; ++fm)
#pragma unroll
    for (int fn = 0; fn < 2; ++fn) {
      int col = colBase + w * 32 + fn * 16 + l16;
#pragma unroll
      for (int r = 0; r < 4; ++r) {
        int row = rowBase + fm * 16 + 4 * g + r;
        out[(size_t)row * DIMc + col] = acc[fm][fn][r] + bias[col];
      }
    }
}

// ---------------- launch ----------------
extern "C" void kernel_launch(void* const* d_in, const int* in_sizes, int n_in,
                              void* d_out, int out_size, void* d_ws, size_t ws_size,
                              hipStream_t stream) {
  const float* x     = (const float*)d_in[0];
  const float* rope  = (const float*)d_in[1];
  const float* w_qkv = (const float*)d_in[2];
  const float* w_out = (const float*)d_in[3];
  const float* b_out = (const float*)d_in[4];
  float* out = (float*)d_out;

  char* ws = (char*)d_ws;
  ushort* xb    = (ushort*)(ws);
  ushort* wqkvT = (ushort*)(ws + 8388608);
  ushort* woutT = (ushort*)(ws + 14680064);
  float2* csT   = (float2*)(ws + 16777216);
  ushort* Qd    = (ushort*)(ws + 17825792);
  ushort* Kd    = (ushort*)(ws + 26214400);
  ushort* Vd    = (ushort*)(ws + 34603008);
  ushort* ao    = (ushort*)(ws + 42991616);

  hipLaunchKernelGGL(k_cast_x, dim3(2048), dim3(256), 0, stream, x, xb, rope, csT);
  hipLaunchKernelGGL(k_transpose_cast, dim3(QKVC / 32, DIMc / 32), dim3(32, 8), 0, stream,
                     w_qkv, wqkvT, DIMc, QKVC);
  hipLaunchKernelGGL(k_transpose_cast, dim3(DIMc / 32, DIMc / 32), dim3(32, 8), 0, stream,
                     w_out, woutT, DIMc, DIMc);
  hipLaunchKernelGGL(k_gemm_qkv, dim3(12, 16), dim3(512), 0, stream,
                     xb, wqkvT, csT, Qd, Kd, Vd);
  hipLaunchKernelGGL(k_attn, dim3(16, Bb * Hh), dim3(256), 0, stream, Qd, Kd, Vd, ao);
  hipLaunchKernelGGL(k_gemm_out, dim3(8, BN / 64), dim3(256), 0, stream,
                     ao, woutT, b_out, out);
}

// Round 17
// 127.694 us; speedup vs baseline: 1.1166x; 1.1166x over previous
//
#include <hip/hip_runtime.h>
#include <stdint.h>

#define DEV __device__ __forceinline__

typedef __bf16 bf16x8 __attribute__((ext_vector_type(8)));
typedef float  f32x4  __attribute__((ext_vector_type(4)));
typedef short  s16x8  __attribute__((ext_vector_type(8)));

constexpr int Bb   = 2;
constexpr int Nn   = 2048;
constexpr int DIMc = 1024;
constexpr int Hh   = 16;
constexpr int DHc  = 64;
constexpr int BN   = Bb * Nn;        // 4096
constexpr int QKVC = 3 * Hh * DHc;   // 3072

// f32 -> bf16 (RNE)
DEV ushort f2b(float f) {
  uint32_t u = __float_as_uint(f);
  u += 0x7fffu + ((u >> 16) & 1u);
  return (ushort)(u >> 16);
}

// async global->LDS, 16B per lane. LDS dest must be wave-uniform base (+lane*16 implicit).
DEV void gload16(const void* g, void* l) {
  __builtin_amdgcn_global_load_lds(
      (const __attribute__((address_space(1))) void*)(uintptr_t)g,
      (__attribute__((address_space(3))) void*)(uint32_t)(uintptr_t)l,
      16, 0, 0);
}

DEV f32x4 mfma16(bf16x8 a, bf16x8 b, f32x4 c) {
  return __builtin_amdgcn_mfma_f32_16x16x32_bf16(a, b, c, 0, 0, 0);
}

DEV uint32_t cvtpk(float lo, float hi) {
  uint32_t r;
  asm("v_cvt_pk_bf16_f32 %0, %1, %2" : "=v"(r) : "v"(lo), "v"(hi));
  return r;
}

// ---------------- prep kernels ----------------

__global__ void k_cast_x(const float* __restrict__ x, ushort* __restrict__ xb,
                         const float* __restrict__ rope, float2* __restrict__ csT) {
  int i = blockIdx.x * 256 + threadIdx.x;
  size_t base = (size_t)i * 8;
  s16x8 v;
#pragma unroll
  for (int j = 0; j < 8; ++j) v[j] = (short)f2b(x[base + j]);
  *(s16x8*)(xb + base) = v;
  if (i < Nn * DHc) {
    float t = rope[i];
    float s, c;
    sincosf(t, &s, &c);
    csT[i] = make_float2(c, s);
  }
}

// fused: bx<96 -> w_qkv (1024x3072), else w_out (1024x1024)
__global__ void k_transpose_both(const float* __restrict__ wqkv, ushort* __restrict__ wqkvT,
                                 const float* __restrict__ wout, ushort* __restrict__ woutT) {
  __shared__ float tile[32][33];
  const int bx = blockIdx.x;
  const float* src; ushort* dst; int Ncols, nb;
  if (bx < 96) { src = wqkv; dst = wqkvT; Ncols = QKVC; nb = bx * 32; }
  else         { src = wout; dst = woutT; Ncols = DIMc; nb = (bx - 96) * 32; }
  const int kb = blockIdx.y * 32;
  int tx = threadIdx.x, ty = threadIdx.y;
#pragma unroll
  for (int i = 0; i < 4; ++i) {
    int k = ty + i * 8;
    tile[k][tx] = src[(size_t)(kb + k) * Ncols + nb + tx];
  }
  __syncthreads();
#pragma unroll
  for (int i = 0; i < 4; ++i) {
    int n = ty + i * 8;
    dst[(size_t)(nb + n) * DIMc + kb + tx] = f2b(tile[tx][n]);
  }
}

// ---------------- GEMM core v3 (R6/R9-verified): 3-buffer, 1 barrier/K-step ----------------
DEV void gemm_core(const ushort* __restrict__ A, const ushort* __restrict__ Bt,
                   int rowBase, int colBase, ushort* lA, ushort* lB,
                   f32x4 (&acc)[4][4]) {
  const int tid = threadIdx.x;
  const int lane = tid & 63, w = tid >> 6;
  const int wm = w >> 1, wn = w & 1;
  const int g = lane >> 4, l16 = lane & 15;
  const f32x4 zero = {0.f, 0.f, 0.f, 0.f};
#pragma unroll
  for (int i = 0; i < 4; ++i)
#pragma unroll
    for (int j = 0; j < 4; ++j) acc[i][j] = zero;

  const int c0row = tid >> 2,          c0kc = (tid & 3) ^ ((c0row >> 1) & 3);
  const int c1row = (256 + tid) >> 2,  c1kc = (tid & 3) ^ ((c1row >> 1) & 3);
  const ushort* gA0 = A  + (size_t)(rowBase + c0row) * DIMc + c0kc * 8;
  const ushort* gA1 = A  + (size_t)(rowBase + c1row) * DIMc + c1kc * 8;
  const ushort* gB0 = Bt + (size_t)(colBase + c0row) * DIMc + c0kc * 8;
  const ushort* gB1 = Bt + (size_t)(colBase + c1row) * DIMc + c1kc * 8;
  const size_t o0 = (size_t)(0 * 256 + w * 64) * 8;
  const size_t o1 = (size_t)(1 * 256 + w * 64) * 8;
  constexpr int BUF = 128 * 32;

  gload16(gA0,      lA + o0);        gload16(gB0,      lB + o0);
  gload16(gA1,      lA + o1);        gload16(gB1,      lB + o1);
  gload16(gA0 + 32, lA + BUF + o0);  gload16(gB0 + 32, lB + BUF + o0);
  gload16(gA1 + 32, lA + BUF + o1);  gload16(gB1 + 32, lB + BUF + o1);
  asm volatile("s_waitcnt vmcnt(4)" ::: "memory");
  __builtin_amdgcn_s_barrier();

  int cur = 0;
  for (int k0 = 0; k0 < DIMc; k0 += 32) {
    const ushort* cA = lA + cur * BUF;
    const ushort* cB = lB + cur * BUF;

    bf16x8 af[4], bfr[4];
#pragma unroll
    for (int f = 0; f < 4; ++f) {
      int r  = wm * 64 + f * 16 + l16;
      int r2 = wn * 64 + f * 16 + l16;
      af[f]  = *(const bf16x8*)&cA[r  * 32 + ((g ^ ((r  >> 1) & 3)) << 3)];
      bfr[f] = *(const bf16x8*)&cB[r2 * 32 + ((g ^ ((r2 >> 1) & 3)) << 3)];
    }

    const int kn = k0 + 64;
    if (kn < DIMc) {
      int st = cur + 2; if (st >= 3) st -= 3;
      ushort* nA = lA + st * BUF;
      ushort* nB = lB + st * BUF;
      gload16(gA0 + kn, nA + o0);  gload16(gB0 + kn, nB + o0);
      gload16(gA1 + kn, nA + o1);  gload16(gB1 + kn, nB + o1);
    }

#pragma unroll
    for (int i = 0; i < 4; ++i)
#pragma unroll
      for (int j = 0; j < 4; ++j)
        acc[i][j] = mfma16(af[i], bfr[j], acc[i][j]);

    if (kn < DIMc) {
      asm volatile("s_waitcnt vmcnt(4)" ::: "memory");
    } else if (k0 + 32 < DIMc) {
      asm volatile("s_waitcnt vmcnt(0)" ::: "memory");
    }
    asm volatile("s_waitcnt lgkmcnt(0)" ::: "memory");
    __builtin_amdgcn_s_barrier();
    cur += 1; if (cur == 3) cur = 0;
  }
}

// ---------------- GEMM1 (R9-exact, no T1): 128x128, fused rotary ----------------
__global__ __launch_bounds__(256) void k_gemm_qkv(
    const ushort* __restrict__ xb, const ushort* __restrict__ wT,
    const float2* __restrict__ csT,
    ushort* __restrict__ Qd, ushort* __restrict__ Kd, ushort* __restrict__ Vd) {
  __shared__ ushort lA[3 * 128 * 32];
  __shared__ ushort lB[3 * 128 * 32];
  f32x4 acc[4][4];
  const int rowBase = blockIdx.y * 128, colBase = blockIdx.x * 128;
  gemm_core(xb, wT, rowBase, colBase, lA, lB, acc);

  const int lane = threadIdx.x & 63, w = threadIdx.x >> 6;
  const int wm = w >> 1, wn = w & 1;
  const int g = lane >> 4, l16 = lane & 15;
#pragma unroll
  for (int fm = 0; fm < 4; ++fm) {
#pragma unroll
    for (int fn = 0; fn < 4; ++fn) {
      int col = colBase + wn * 64 + fn * 16 + l16;
      int sel = col >> 10, hc = col & 1023;
      int h = hc >> 6, d = hc & 63;
      float sgn = (d & 1) ? 1.f : -1.f;
#pragma unroll
      for (int r = 0; r < 4; ++r) {
        float t  = acc[fm][fn][r];
        float tp = __shfl_xor(t, 1);
        int row = rowBase + wm * 64 + fm * 16 + 4 * g + r;
        int b = row >> 11, n = row & 2047;
        float2 cs = csT[n * 64 + d];
        float rv = t * cs.x + sgn * tp * cs.y;
        if (sel == 0) {
          Qd[((size_t)(b * Hh + h) * Nn + n) * DHc + d] = f2b(rv * 0.125f);
        } else if (sel == 1) {
          Kd[((size_t)(b * Hh + h) * Nn + n) * DHc + d] = f2b(rv);
        } else {
          Vd[((size_t)(b * Hh + h) * DHc + d) * Nn + n] = f2b(rv);
        }
      }
    }
  }
}

// ---------------- attention (R14-verified: paired + T1 XCD swizzle) + T5 setprio ----------------

DEV void stageKV(const ushort* __restrict__ Kh, const ushort* __restrict__ Vh,
                 ushort* lKb, ushort* lVb, int kt, int tid, int w) {
#pragma unroll
  for (int s = 0; s < 2; ++s) {
    int c = s * 256 + tid;
    int row = c >> 3, jst = c & 7;
    int jl = jst ^ (row & 7);
    gload16(Kh + (size_t)(kt * 64 + row) * DHc + jl * 8,
            lKb + (size_t)(s * 256 + w * 64) * 8);
    gload16(Vh + (size_t)row * Nn + kt * 64 + jl * 8,
            lVb + (size_t)(s * 256 + w * 64) * 8);
  }
}

DEV void attn_step(const ushort* lKc, const ushort* lVc, char* lPw,
                   const bf16x8 (&q)[2], f32x4 (&o)[4], float& m, float& l,
                   int kBase, int qg, bool diag, int g, int l16) {
  const f32x4 zero = {0.f, 0.f, 0.f, 0.f};
  f32x4 s[4];
#pragma unroll
  for (int jt = 0; jt < 4; ++jt) s[jt] = zero;

  __builtin_amdgcn_s_setprio(1);               // T5: favor MFMA cluster
#pragma unroll
  for (int jt = 0; jt < 4; ++jt) {
    int jr = jt * 16 + l16;
#pragma unroll
    for (int d0 = 0; d0 < 2; ++d0) {
      bf16x8 kb = *(const bf16x8*)&lKc[jr * 64 + (((d0 * 4 + g) ^ (jr & 7)) << 3)];
      s[jt] = mfma16(kb, q[d0], s[jt]);
    }
  }
  __builtin_amdgcn_s_setprio(0);

  if (diag) {
#pragma unroll
    for (int jt = 0; jt < 4; ++jt)
#pragma unroll
      for (int r = 0; r < 4; ++r) {
        int j = kBase + jt * 16 + 4 * g + r;
        if (j > qg) s[jt][r] = -3.0e38f;
      }
  }

  float tmax = fmaxf(fmaxf(fmaxf(s[0][0], s[0][1]), fmaxf(s[0][2], s[0][3])),
                     fmaxf(fmaxf(s[1][0], s[1][1]), fmaxf(s[1][2], s[1][3])));
  tmax = fmaxf(tmax, fmaxf(fmaxf(fmaxf(s[2][0], s[2][1]), fmaxf(s[2][2], s[2][3])),
                           fmaxf(fmaxf(s[3][0], s[3][1]), fmaxf(s[3][2], s[3][3]))));
  tmax = fmaxf(tmax, __shfl_xor(tmax, 16));
  tmax = fmaxf(tmax, __shfl_xor(tmax, 32));

  if (!__all(tmax <= m + 8.f)) {
    float mnew = fmaxf(m, tmax);
    float sc = __expf(m - mnew);
#pragma unroll
    for (int dt = 0; dt < 4; ++dt) o[dt] *= sc;
    l *= sc;
    m = mnew;
  }

  float ps = 0.f;
#pragma unroll
  for (int jt = 0; jt < 4; ++jt)
#pragma unroll
    for (int r = 0; r < 4; ++r) {
      float p = __expf(s[jt][r] - m);
      s[jt][r] = p;
      ps += p;
    }
  ps += __shfl_xor(ps, 16);
  ps += __shfl_xor(ps, 32);
  l += ps;

  const int sw = (l16 & 7) << 4;
  char* prow = lPw + l16 * 128;
#pragma unroll
  for (int jt = 0; jt < 4; ++jt) {
    int jo = (jt * 16 + 4 * g) * 2;
    *(uint32_t*)(prow + (jo ^ sw))       = cvtpk(s[jt][0], s[jt][1]);
    *(uint32_t*)(prow + ((jo + 4) ^ sw)) = cvtpk(s[jt][2], s[jt][3]);
  }

  bf16x8 pa[2];
#pragma unroll
  for (int jh = 0; jh < 2; ++jh)
    pa[jh] = *(const bf16x8*)(prow + (((jh * 32 + 8 * g) * 2) ^ sw));
  __builtin_amdgcn_s_setprio(1);               // T5: favor MFMA cluster
#pragma unroll
  for (int dt = 0; dt < 4; ++dt) {
    int d = dt * 16 + l16;
#pragma unroll
    for (int jh = 0; jh < 2; ++jh) {
      bf16x8 vb = *(const bf16x8*)&lVc[d * 64 + (((jh * 4 + g) ^ (d & 7)) << 3)];
      o[dt] = mfma16(vb, pa[jh], o[dt]);
    }
  }
  __builtin_amdgcn_s_setprio(0);
}

DEV void attn_epi(ushort* __restrict__ ao, int bh, int n, int g,
                  f32x4 (&o)[4], float l) {
  const int b = bh >> 4, h = bh & 15;
  float inv = 1.f / l;
  ushort* dst = ao + (size_t)(b * Nn + n) * (Hh * DHc) + h * 64;
#pragma unroll
  for (int dt = 0; dt < 4; ++dt) {
    uint2 pkd;
    pkd.x = cvtpk(o[dt][0] * inv, o[dt][1] * inv);
    pkd.y = cvtpk(o[dt][2] * inv, o[dt][3] * inv);
    *(uint2*)(dst + dt * 16 + 4 * g) = pkd;
  }
}

__global__ __launch_bounds__(256) void k_attn(
    const ushort* __restrict__ Qd, const ushort* __restrict__ Kd,
    const ushort* __restrict__ Vd, ushort* __restrict__ ao) {
  __shared__ ushort lK[2][64 * 64];
  __shared__ ushort lV[2][64 * 64];
  __shared__ char   lP[4][16 * 128];
  const int tid = threadIdx.x;
  const int lane = tid & 63, w = tid >> 6;
  const int g = lane >> 4, l16 = lane & 15;
  const int i = blockIdx.x + blockIdx.y * 16;
  const int c = i & 7, li = i >> 3;
  const int bh = c * 4 + (li >> 4);
  const int p = li & 15;
  const int tA = p, tB = 31 - p;
  const int last = tB;
  const ushort* Qh = Qd + (size_t)bh * Nn * DHc;
  const ushort* Kh = Kd + (size_t)bh * Nn * DHc;
  const ushort* Vh = Vd + (size_t)bh * DHc * Nn;

  const int qgA = tA * 64 + w * 16 + l16;
  const int qgB = tB * 64 + w * 16 + l16;

  bf16x8 qA[2], qB[2];
#pragma unroll
  for (int d0 = 0; d0 < 2; ++d0) {
    qA[d0] = *(const bf16x8*)(Qh + (size_t)qgA * DHc + d0 * 32 + g * 8);
    qB[d0] = *(const bf16x8*)(Qh + (size_t)qgB * DHc + d0 * 32 + g * 8);
  }

  const f32x4 zero = {0.f, 0.f, 0.f, 0.f};
  f32x4 oA[4], oB[4];
#pragma unroll
  for (int dt = 0; dt < 4; ++dt) { oA[dt] = zero; oB[dt] = zero; }
  float mA = -3.0e38f, lA_ = 0.f, mB = -3.0e38f, lB_ = 0.f;

  stageKV(Kh, Vh, lK[0], lV[0], 0, tid, w);

  for (int kt = 0; kt <= last; ++kt) {
    const int cur = kt & 1;
    if (kt < last) {
      stageKV(Kh, Vh, lK[cur ^ 1], lV[cur ^ 1], kt + 1, tid, w);
      asm volatile("s_waitcnt vmcnt(4)" ::: "memory");
    } else {
      asm volatile("s_waitcnt vmcnt(0)" ::: "memory");
    }
    __builtin_amdgcn_s_barrier();

    attn_step(lK[cur], lV[cur], lP[w], qB, oB, mB, lB_, kt * 64, qgB, kt == tB, g, l16);
    if (kt <= tA)
      attn_step(lK[cur], lV[cur], lP[w], qA, oA, mA, lA_, kt * 64, qgA, kt == tA, g, l16);

    __builtin_amdgcn_s_barrier();
  }

  attn_epi(ao, bh, qgA, g, oA, lA_);
  attn_epi(ao, bh, qgB, g, oB, lB_);
}

// ---------------- GEMM2 (R14-verified): 64x128 tiles + T1 XCD swizzle ----------------
__global__ __launch_bounds__(256) void k_gemm_out(
    const ushort* __restrict__ ao, const ushort* __restrict__ wT,
    const float* __restrict__ bias, float* __restrict__ out) {
  __shared__ ushort lA[3 * 64 * 32];
  __shared__ ushort lB[3 * 128 * 32];
  const int tid = threadIdx.x;
  const int lane = tid & 63, w = tid >> 6;
  const int g = lane >> 4, l16 = lane & 15;
  const int i = blockIdx.x + blockIdx.y * 8;
  const int c = i & 7, li = i >> 3;
  const int bx = (c & 3) * 2 + (li & 1);
  const int by = (c >> 2) * 32 + (li >> 1);
  const int rowBase = by * 64, colBase = bx * 128;

  f32x4 acc[4][2];
  const f32x4 zero = {0.f, 0.f, 0.f, 0.f};
#pragma unroll
  for (int i2 = 0; i2 < 4; ++i2) { acc[i2][0] = zero; acc[i2][1] = zero; }

  const int arow = tid >> 2, akc = (tid & 3) ^ ((arow >> 1) & 3);
  const int b1row = 64 + arow, b1kc = (tid & 3) ^ ((b1row >> 1) & 3);
  const ushort* gA  = ao + (size_t)(rowBase + arow) * DIMc + akc * 8;
  const ushort* gB0 = wT + (size_t)(colBase + arow) * DIMc + akc * 8;
  const ushort* gB1 = wT + (size_t)(colBase + b1row) * DIMc + b1kc * 8;
  const size_t oA  = (size_t)w * 512;
  const size_t oB0 = (size_t)w * 512;
  const size_t oB1 = 2048 + (size_t)w * 512;
  constexpr int BUFA = 64 * 32, BUFB = 128 * 32;

  gload16(gA,      lA + oA);         gload16(gB0,      lB + oB0);         gload16(gB1,      lB + oB1);
  gload16(gA + 32, lA + BUFA + oA);  gload16(gB0 + 32, lB + BUFB + oB0);  gload16(gB1 + 32, lB + BUFB + oB1);
  asm volatile("s_waitcnt vmcnt(3)" ::: "memory");
  __builtin_amdgcn_s_barrier();

  int cur = 0;
  for (int k0 = 0; k0 < DIMc; k0 += 32) {
    const ushort* cA = lA + cur * BUFA;
    const ushort* cB = lB + cur * BUFB;

    bf16x8 af[4], bfr[2];
#pragma unroll
    for (int f = 0; f < 4; ++f) {
      int r = f * 16 + l16;
      af[f] = *(const bf16x8*)&cA[r * 32 + ((g ^ ((r >> 1) & 3)) << 3)];
    }
#pragma unroll
    for (int f = 0; f < 2; ++f) {
      int r2 = w * 32 + f * 16 + l16;
      bfr[f] = *(const bf16x8*)&cB[r2 * 32 + ((g ^ ((r2 >> 1) & 3)) << 3)];
    }

    const int kn = k0 + 64;
    if (kn < DIMc) {
      int st = cur + 2; if (st >= 3) st -= 3;
      gload16(gA + kn,  lA + st * BUFA + oA);
      gload16(gB0 + kn, lB + st * BUFB + oB0);
      gload16(gB1 + kn, lB + st * BUFB + oB1);
    }

#pragma unroll
    for (int i2 = 0; i2 < 4; ++i2)
#pragma unroll
      for (int j = 0; j < 2; ++j)
        acc[i2][j] = mfma16(af[i2], bfr[j], acc[i2][j]);

    if (kn < DIMc) {
      asm volatile("s_waitcnt vmcnt(3)" ::: "memory");
    } else if (k0 + 32 < DIMc) {
      asm volatile("s_waitcnt vmcnt(0)" ::: "memory");
    }
    asm volatile("s_waitcnt lgkmcnt(0)" ::: "memory");
    __builtin_amdgcn_s_barrier();
    cur += 1; if (cur == 3) cur = 0;
  }

#pragma unroll
  for (int fm = 0; fm < 4; ++fm)
#pragma unroll
    for (int fn = 0; fn < 2; ++fn) {
      int col = colBase + w * 32 + fn * 16 + l16;
#pragma unroll
      for (int r = 0; r < 4; ++r) {
        int row = rowBase + fm * 16 + 4 * g + r;
        out[(size_t)row * DIMc + col] = acc[fm][fn][r] + bias[col];
      }
    }
}

// ---------------- launch ----------------
extern "C" void kernel_launch(void* const* d_in, const int* in_sizes, int n_in,
                              void* d_out, int out_size, void* d_ws, size_t ws_size,
                              hipStream_t stream) {
  const float* x     = (const float*)d_in[0];
  const float* rope  = (const float*)d_in[1];
  const float* w_qkv = (const float*)d_in[2];
  const float* w_out = (const float*)d_in[3];
  const float* b_out = (const float*)d_in[4];
  float* out = (float*)d_out;

  char* ws = (char*)d_ws;
  ushort* xb    = (ushort*)(ws);
  ushort* wqkvT = (ushort*)(ws + 8388608);
  ushort* woutT = (ushort*)(ws + 14680064);
  float2* csT   = (float2*)(ws + 16777216);
  ushort* Qd    = (ushort*)(ws + 17825792);
  ushort* Kd    = (ushort*)(ws + 26214400);
  ushort* Vd    = (ushort*)(ws + 34603008);
  ushort* ao    = (ushort*)(ws + 42991616);

  hipLaunchKernelGGL(k_cast_x, dim3(2048), dim3(256), 0, stream, x, xb, rope, csT);
  hipLaunchKernelGGL(k_transpose_both, dim3(128, 32), dim3(32, 8), 0, stream,
                     w_qkv, wqkvT, w_out, woutT);
  hipLaunchKernelGGL(k_gemm_qkv, dim3(QKVC / 128, BN / 128), dim3(256), 0, stream,
                     xb, wqkvT, csT, Qd, Kd, Vd);
  hipLaunchKernelGGL(k_attn, dim3(16, Bb * Hh), dim3(256), 0, stream, Qd, Kd, Vd, ao);
  hipLaunchKernelGGL(k_gemm_out, dim3(8, BN / 64), dim3(256), 0, stream,
                     ao, woutT, b_out, out);
}